// Round 13
// baseline (357.953 us; speedup 1.0000x reference)
//
#include <hip/hip_runtime.h>
#include <hip/hip_bf16.h>
#include <stdint.h>

#define BB 16
#define NZ 2048
#define NE 2048
#define DD 512

typedef unsigned short u16;
typedef __attribute__((ext_vector_type(8))) _Float16 f16x8;   // 8 fp16 = 4 VGPR
typedef __attribute__((ext_vector_type(4))) float f32x4;
typedef __attribute__((ext_vector_type(16))) float f32x16;    // 32x32 acc

__device__ __forceinline__ u16 f2h(float f) {
  _Float16 h = (_Float16)f;                 // v_cvt_f16_f32, RNE
  return __builtin_bit_cast(u16, h);
}

// Fragment-pack format for a logical fp16 operand X[R][K] consumed by
// mfma_f32_32x32x16_f16 (A or B side, both read as [row][k]):
//   frag(rf, kt) = 1 KB block at ((rf*KT + kt) * 512) u16;
//   lane l holds X[rf*32 + (l&31)][kt*16 + (l>>5)*8 + j], j=0..7, at +l*8 u16.
// A wave's fragment load = ONE coalesced global_load_dwordx4. [layout verified
// by r12's passing 32x32x16 kernel, which used the same operand mapping]

// ---------- k_packA: X f32 [R][512] -> frag-pack fp16 (rows = source rows) ----------
__global__ void k_packA(const float* __restrict__ X, u16* __restrict__ FP) {
  __shared__ u16 sm[32 * 512];   // chunk-swizzled: phys16B = c ^ (row&7)
  const int t = threadIdx.x;
  const long long r0 = (long long)blockIdx.x * 32;
#pragma unroll
  for (int i = 0; i < 16; ++i) {
    int flat4 = i * 256 + t;          // 0..4095 float4s
    int row = flat4 >> 7;
    int c4 = flat4 & 127;
    float4 v = ((const float4*)(X + (r0 + row) * 512))[c4];
    int phys = (c4 >> 1) ^ (row & 7);
    u16* p = &sm[row * 512 + phys * 8 + (c4 & 1) * 4];
    p[0] = f2h(v.x); p[1] = f2h(v.y); p[2] = f2h(v.z); p[3] = f2h(v.w);
  }
  __syncthreads();
  const int lane = t & 63, wid = t >> 6;
  const int l31 = lane & 31, hi2 = lane >> 5;
#pragma unroll
  for (int q = 0; q < 8; ++q) {
    int kt = wid * 8 + q;             // 0..31
    int phys = (kt * 2 + hi2) ^ (l31 & 7);
    f16x8 v = *(const f16x8*)&sm[l31 * 512 + phys * 8];
    *(f16x8*)(FP + (((long long)blockIdx.x * 32 + kt) << 9) + lane * 8) = v;
  }
}

// ---------- k_packMt: M f32 [512][512] -> Mt_fp (rows = out-col e, k = d) ----------
__global__ void k_packMt(const float* __restrict__ M, u16* __restrict__ FP) {
  __shared__ u16 sm[32 * 128];
  const int t = threadIdx.x;
  const int e0 = blockIdx.x * 32;
  const int d0 = blockIdx.y * 128;
#pragma unroll
  for (int i = 0; i < 4; ++i) {
    int dl = i * 32 + (t >> 3);       // 0..127
    int el = (t & 7) * 4;
    float4 v = *(const float4*)(M + (size_t)(d0 + dl) * 512 + e0 + el);
    float vv[4] = {v.x, v.y, v.z, v.w};
#pragma unroll
    for (int jj = 0; jj < 4; ++jj) {
      int er = el + jj;
      int phys = (dl >> 3) ^ (er & 7);
      sm[er * 128 + phys * 8 + (dl & 7)] = f2h(vv[jj]);
    }
  }
  __syncthreads();
  const int lane = t & 63, wid = t >> 6;
  const int l31 = lane & 31, hi2 = lane >> 5;
#pragma unroll
  for (int ff = 0; ff < 2; ++ff) {
    int f = wid * 2 + ff;             // 0..7
    int phys = (f * 2 + hi2) ^ (l31 & 7);
    f16x8 v = *(const f16x8*)&sm[l31 * 128 + phys * 8];
    int kt = blockIdx.y * 8 + f;      // 0..31
    *(f16x8*)(FP + (((long long)blockIdx.x * 32 + kt) << 9) + lane * 8) = v;
  }
}

// ---------- k_etp: e f32 + colsum -> eT_fp (rows = d, k = m, scaled) ----------
__global__ void k_etp(const float* __restrict__ e, const float* __restrict__ cs,
                      u16* __restrict__ FP) {
  __shared__ u16 sm[32 * 128];
  const int t = threadIdx.x;
  const int b = blockIdx.z;
  const int d0 = blockIdx.x * 32;
  const int m0 = blockIdx.y * 128;
  const float* eb = e + (size_t)b * NE * DD;
  const float* csb = cs + (size_t)b * NE;
#pragma unroll
  for (int i = 0; i < 4; ++i) {
    int ml = i * 32 + (t >> 3);       // 0..127
    int dl = (t & 7) * 4;
    float4 v = *(const float4*)(eb + (size_t)(m0 + ml) * DD + d0 + dl);
    float sc = 2048.0f / csb[m0 + ml];
    float vv[4] = {v.x * sc, v.y * sc, v.z * sc, v.w * sc};
#pragma unroll
    for (int jj = 0; jj < 4; ++jj) {
      int dr = dl + jj;
      int phys = (ml >> 3) ^ (dr & 7);
      sm[dr * 128 + phys * 8 + (ml & 7)] = f2h(vv[jj]);
    }
  }
  __syncthreads();
  const int lane = t & 63, wid = t >> 6;
  const int l31 = lane & 31, hi2 = lane >> 5;
#pragma unroll
  for (int ff = 0; ff < 2; ++ff) {
    int f = wid * 2 + ff;
    int phys = (f * 2 + hi2) ^ (l31 & 7);
    f16x8 v = *(const f16x8*)&sm[l31 * 128 + phys * 8];
    int kt = blockIdx.y * 8 + f;      // 0..127
    *(f16x8*)(FP + (long long)b * 1048576LL +
              (((long long)blockIdx.x * 128 + kt) << 9) + lane * 8) = v;
  }
}

// ---------- barrier-free frag-streaming GEMM ----------
// C = A[M x K] * Bt[N x K]^T, operands frag-packed.  Block = 128 rows x 256
// cols, 256 threads = 4 waves (col-split: wave wc owns cols wc*64).  Per wave:
// 4 rf x 2 cf of 32x32, acc = 128 VGPR.  Per K-step(16): 6 coalesced frag
// loads + 8 MFMA, double-buffered in regs, NO LDS / NO barriers in the loop —
// pure compiler-scheduled stream; 2 blocks/CU via launch_bounds(256,2).
// EPI: 0 = frag-pack fp16 out; 1 = exp(sigmoid) frag-pack + colsum atomics;
//      2 = f32/2048 row-major out (cKT = Ndim).
template<int EPI>
__global__ __launch_bounds__(256, 2) void k_gemm(
    const u16* __restrict__ Afp, const u16* __restrict__ Bfp, void* __restrict__ Cp,
    int KT, long long sAb, long long sBb, long long sCb,
    int cKT, float* __restrict__ colsum, int csld)
{
  extern __shared__ char lds[];

  // bijective XCD-aware swizzle (nwg % 8 == 0 for all our launches)
  const int gx = gridDim.x, gy = gridDim.y;
  const int nwg = gx * gy * gridDim.z;
  const int hid = blockIdx.x + gx * (blockIdx.y + gy * blockIdx.z);
  const int logical = (hid & 7) * (nwg >> 3) + (hid >> 3);
  const int bx = logical % gx;
  const int rem0 = logical / gx;
  const int by = rem0 % gy;
  const int bz = rem0 / gy;

  const int tid = threadIdx.x;
  const int lane = tid & 63;
  const int wid = tid >> 6;
  const int wc = wid;                  // 0..3
  const int l31 = lane & 31, hi2 = lane >> 5;
  const int lane8 = lane * 8;

  const u16* Ab = Afp + bz * sAb;
  const u16* Bb = Bfp + bz * sBb;
  const long long aoff = ((long long)by * 4) * KT;
  const long long boff = ((long long)(bx * 8 + wc * 2)) * KT;

  f32x16 acc[4][2] = {};
  f16x8 a0[4], b0[2], a1[4], b1[2];

#define LSET(ar, br, tt) do { \
    _Pragma("unroll") for (int mf = 0; mf < 4; ++mf) \
      ar[mf] = *(const f16x8*)(Ab + ((aoff + (long long)mf * KT + (tt)) << 9) + lane8); \
    br[0] = *(const f16x8*)(Bb + ((boff + (tt)) << 9) + lane8); \
    br[1] = *(const f16x8*)(Bb + ((boff + KT + (tt)) << 9) + lane8); \
  } while (0)
#define MSET(ar, br) do { \
    _Pragma("unroll") for (int mf = 0; mf < 4; ++mf) { \
      acc[mf][0] = __builtin_amdgcn_mfma_f32_32x32x16_f16(ar[mf], br[0], acc[mf][0], 0, 0, 0); \
      acc[mf][1] = __builtin_amdgcn_mfma_f32_32x32x16_f16(ar[mf], br[1], acc[mf][1], 0, 0, 0); \
    } } while (0)

  LSET(a0, b0, 0);
  for (int t = 0; t < KT; t += 2) {
    LSET(a1, b1, t + 1);
    MSET(a0, b0);
    if (t + 2 < KT) LSET(a0, b0, t + 2);
    MSET(a1, b1);
  }
#undef LSET
#undef MSET

  // C/D layout (32x32): col = lane&31, row = (reg&3)+8*(reg>>2)+4*(lane>>5)
  if constexpr (EPI == 0 || EPI == 1) {
    // stage wave-tile u16 [128][64] in LDS (chunk-swizzled), then write
    // frag-packed: 16 coalesced 1KB stores per wave.
    char* wb = lds + wid * 16384;
    float csum[2] = {0.f, 0.f};
#pragma unroll
    for (int rf = 0; rf < 4; ++rf)
#pragma unroll
      for (int cf = 0; cf < 2; ++cf)
#pragma unroll
        for (int reg = 0; reg < 16; ++reg) {
          float x = acc[rf][cf][reg];
          float v;
          if constexpr (EPI == 1) {
            float s = 1.f / (1.f + __expf(-x));   // sigmoid
            v = __expf(s);                        // in (1, e)
            csum[cf] += v;
          } else {
            v = x;
          }
          int rowl = rf * 32 + (reg & 3) + 8 * (reg >> 2) + 4 * hi2;  // 0..127
          int coll = cf * 32 + l31;                                   // 0..63
          int chunk = (coll >> 3) ^ (rowl & 7);
          *(u16*)(wb + rowl * 128 + chunk * 16 + ((coll * 2) & 15)) = f2h(v);
        }
    if constexpr (EPI == 1) {
#pragma unroll
      for (int cf = 0; cf < 2; ++cf) {
        float v = csum[cf];
        v += __shfl_xor(v, 32, 64);
        if (hi2 == 0)
          atomicAdd(&colsum[(long long)bz * csld + bx * 256 + wc * 64 + cf * 32 + l31], v);
      }
    }
    __syncthreads();   // cross-lane LDS write->read ordering (r6 rule)
    u16* Cu = (u16*)Cp + bz * sCb;
#pragma unroll
    for (int f = 0; f < 16; ++f) {
      int rfl = f >> 2, mtl = f & 3;
      int rowl = rfl * 32 + l31;
      int phys = (mtl * 2 + hi2) ^ (rowl & 7);
      f16x8 v = *(const f16x8*)(wb + rowl * 128 + phys * 16);
      long long base = (((long long)(by * 4 + rfl)) * cKT + (bx * 16 + wc * 4 + mtl)) * 512;
      *(f16x8*)(Cu + base + lane8) = v;
    }
  } else {
    // f32 row-major out (cKT = Ndim): two 64-row passes, coalesced dwordx4
    float* C = (float*)Cp + bz * sCb;
    char* wb = lds + wid * 16384;
#pragma unroll
    for (int h = 0; h < 2; ++h) {
      if (h) __syncthreads();
#pragma unroll
      for (int mm = 0; mm < 2; ++mm) {
        int rf = h * 2 + mm;
#pragma unroll
        for (int cf = 0; cf < 2; ++cf)
#pragma unroll
          for (int reg = 0; reg < 16; ++reg) {
            int rowf = (reg & 3) + 8 * (reg >> 2) + 4 * hi2;
            int rl = mm * 32 + rowf;             // 0..63
            int col = cf * 32 + l31;             // 0..63
            int chunk = (col >> 2) ^ (rl & 15);
            *(float*)(wb + rl * 256 + chunk * 16 + ((col * 4) & 15)) =
                acc[rf][cf][reg] * (1.0f / 2048.0f);
          }
      }
      __syncthreads();
#pragma unroll
      for (int s = 0; s < 16; ++s) {
        int rl = (lane >> 4) + s * 4;            // 0..63
        int chunk = (lane & 15) ^ (rl & 15);
        f32x4 v = *(const f32x4*)(wb + rl * 256 + chunk * 16);
        *(f32x4*)(&C[(long long)(by * 128 + h * 64 + rl) * cKT +
                     bx * 256 + wc * 64 + (lane & 15) * 4]) = v;
      }
    }
  }
}

// ---------- launch ----------
// ws layout (bytes):
//   S_fp    @ 0          : 134217728   (16 x [64 rf][128 kt] x 1KB)
//   zM_fp   @ 134217728  :  33554432
//   zH_fp   @ 167772160  :  33554432   (reused as eT_fp after gemm2)
//   eH_fp   @ 201326592  :  33554432
//   Mt_fp   @ 234881024  :    524288
//   colsum  @ 235405312  :    131072
extern "C" void kernel_launch(void* const* d_in, const int* in_sizes, int n_in,
                              void* d_out, int out_size, void* d_ws, size_t ws_size,
                              hipStream_t stream) {
  const float* z = (const float*)d_in[0];
  const float* e = (const float*)d_in[1];
  const float* M = (const float*)d_in[2];
  float* out = (float*)d_out;
  char* ws = (char*)d_ws;

  u16* S_fp  = (u16*)(ws + 0LL);
  u16* zM_fp = (u16*)(ws + 134217728LL);
  u16* zH_fp = (u16*)(ws + 167772160LL);
  u16* eH_fp = (u16*)(ws + 201326592LL);
  u16* Mt_fp = (u16*)(ws + 234881024LL);
  float* cs  = (float*)(ws + 235405312LL);
  u16* eT_fp = zH_fp;   // zH_fp dead after gemm1

  (void)hipFuncSetAttribute(reinterpret_cast<const void*>(&k_gemm<0>),
                            hipFuncAttributeMaxDynamicSharedMemorySize, 65536);
  (void)hipFuncSetAttribute(reinterpret_cast<const void*>(&k_gemm<1>),
                            hipFuncAttributeMaxDynamicSharedMemorySize, 65536);
  (void)hipFuncSetAttribute(reinterpret_cast<const void*>(&k_gemm<2>),
                            hipFuncAttributeMaxDynamicSharedMemorySize, 65536);

  hipMemsetAsync(cs, 0, (size_t)BB * NE * sizeof(float), stream);

  // pack inputs into fragment order
  k_packA<<<1024, 256, 0, stream>>>(z, zH_fp);          // 32768 rows
  k_packA<<<1024, 256, 0, stream>>>(e, eH_fp);          // 32768 rows
  k_packMt<<<dim3(16, 4), 256, 0, stream>>>(M, Mt_fp);

  // gemm1: zM_fp = zH_fp @ Mt_fp^T  (batch-folded; KT=32, C cKT=32)
  k_gemm<0><<<dim3(2, 256, 1), 256, 65536, stream>>>(
      zH_fp, Mt_fp, zM_fp, 32, 0LL, 0LL, 0LL, 32, nullptr, 0);

  // gemm2: S_fp = exp(sigmoid(zM @ eH^T)) + colsum  (KT=32, C cKT=128)
  k_gemm<1><<<dim3(8, 16, 16), 256, 65536, stream>>>(
      zM_fp, eH_fp, S_fp, 32, 1048576LL, 1048576LL, 4194304LL, 128, cs, NE);

  // eT_fp[d][m] = fp16(e[m][d] * 2048 / colsum[m])
  k_etp<<<dim3(16, 16, 16), 256, 0, stream>>>(e, cs, eT_fp);

  // gemm3: out = (S_fp @ eT_fp^T) / 2048  (KT=128, f32 out Ndim=512)
  k_gemm<2><<<dim3(2, 16, 16), 256, 65536, stream>>>(
      S_fp, eT_fp, out, 128, 4194304LL, 1048576LL, (long long)NZ * DD, 512, nullptr, 0);
}

// Round 15
// 278.023 us; speedup vs baseline: 1.2875x; 1.2875x over previous
//
#include <hip/hip_runtime.h>
#include <hip/hip_bf16.h>
#include <stdint.h>

#define BB 16
#define NZ 2048
#define NE 2048
#define DD 512

typedef unsigned short u16;
typedef __attribute__((ext_vector_type(8))) _Float16 f16x8;  // 8 fp16 = 4 VGPR
typedef __attribute__((ext_vector_type(4))) float f32x4;

// ---------- helpers ----------
__device__ __forceinline__ u16 f2h(float f) {
  _Float16 h = (_Float16)f;                 // v_cvt_f16_f32, RNE
  return __builtin_bit_cast(u16, h);
}

__device__ __forceinline__ float h2f(u16 h) {
  return (float)__builtin_bit_cast(_Float16, h);
}

__device__ __forceinline__ void gload_lds16(const void* g, void* l) {
  auto gp = (const __attribute__((address_space(1))) uint32_t*)g;
  auto lp = (__attribute__((address_space(3))) uint32_t*)l;
  __builtin_amdgcn_global_load_lds(gp, lp, 16, 0, 0);
}

#define FENCE() asm volatile("" ::: "memory")
#define BARRIER() do { FENCE(); __builtin_amdgcn_s_barrier(); FENCE(); } while (0)
#define WAIT_LGKM0() asm volatile("s_waitcnt lgkmcnt(0)" ::: "memory")
#define WAIT_VM(n) asm volatile("s_waitcnt vmcnt(" #n ")" ::: "memory")

// ---------- f32 -> fp16 bulk convert ----------
__global__ void k_cvt(const float* __restrict__ in, u16* __restrict__ out, int n4) {
  int i = blockIdx.x * blockDim.x + threadIdx.x;
  int stride = gridDim.x * blockDim.x;
  for (; i < n4; i += stride) {
    float4 v = ((const float4*)in)[i];
    ushort4 o;
    o.x = f2h(v.x); o.y = f2h(v.y); o.z = f2h(v.z); o.w = f2h(v.w);
    ((ushort4*)out)[i] = o;
  }
}

// ---------- M[512x512] -> Mt fp16 (Mt[e][d] = M[d][e]) ----------
__global__ void k_mt(const float* __restrict__ M, u16* __restrict__ Mt) {
  __shared__ float t[32][33];
  int bx = blockIdx.x * 32;  // e range
  int by = blockIdx.y * 32;  // d range
  for (int r = 0; r < 32; r += 8)
    t[threadIdx.y + r][threadIdx.x] = M[(size_t)(by + threadIdx.y + r) * DD + bx + threadIdx.x];
  __syncthreads();
  for (int r = 0; r < 32; r += 8)
    Mt[(size_t)(bx + threadIdx.y + r) * DD + by + threadIdx.x] = f2h(t[threadIdx.x][threadIdx.y + r]);
}

// ---------- eT'[b][d][m] = fp16( eH[b][m][d] * 2048 / colsum[b][m] ) ----------
__global__ void k_et(const u16* __restrict__ eH, const float* __restrict__ cs,
                     u16* __restrict__ eT) {
  __shared__ float t[32][33];
  int b = blockIdx.z;
  int m0 = blockIdx.y * 32, d0 = blockIdx.x * 32;
  const u16* eb = eH + (size_t)b * NE * DD;
  const float* csb = cs + (size_t)b * NE;
  for (int r = 0; r < 32; r += 8) {
    int m = m0 + threadIdx.y + r;
    t[threadIdx.y + r][threadIdx.x] =
        h2f(eb[(size_t)m * DD + d0 + threadIdx.x]) * (2048.0f / csb[m]);
  }
  __syncthreads();
  u16* eTb = eT + (size_t)b * DD * NE;
  for (int r = 0; r < 32; r += 8) {
    int d = d0 + threadIdx.y + r;
    eTb[(size_t)d * NE + m0 + threadIdx.x] = f2h(t[threadIdx.x][threadIdx.y + r]);
  }
}

// ---------- 256x256 tile, BK=64, 8-wave, 4-phase template + coalesced XOR LDS --
// C = A[M x K] * Bt[N x K]^T.  512 threads = 8 waves (2M x 4N), per-wave 128x64
// = 8m x 4n frags of 16x16x32.  LDS 128 KiB: A dbuf{0,1} @ {0,32768},
// B dbuf @ {65536, 98304}; within a buf: ks-half @ ks*16384, then linear
// 64-B rows with XOR chunk swizzle cw = c ^ ((r>>1)&3)  [r9-r11 verified:
// coalesced global_load_lds staging AND conflict-free ds_read_b128].
// Per K-tile t (4 phases, m201/r4 schedule — first time WITH coalesced LDS):
//  P0: read A(m0-3,ks0)4 + B(n0-3,ks0)4; stage A-ks0(t+1); BAR; lgkm0;
//      setprio1; 16 MFMA; setprio0; BAR
//  P1: read A(m4-7,ks0)4;                stage B-ks0(t+1); BAR; lgkm0;
//      setprio1; 16 MFMA; setprio0; VM(4) [this tile's ks1 landed]; BAR
//  P2: read A(m0-3,ks1)4 + B(n0-3,ks1)4; stage A-ks1(t+1); ... BAR
//  P3: read A(m4-7,ks1)4;                stage B-ks1(t+1); ...
//      VM(4) [next tile's ks0 landed]; BAR
// vmcnt counted, never 0 in steady state (4 loads always in flight).
// EPI: 0 = fp16 out; 1 = exp(sigmoid(x)) fp16 out + colsum atomics; 2 = f32/2048
template<int EPI, int KDIM>
__global__ __launch_bounds__(512, 2) void k_gemm(
    const u16* __restrict__ A, const u16* __restrict__ Bt, void* __restrict__ Cp,
    int Ndim, long long sAb, long long sBb, long long sCb,
    float* __restrict__ colsum, int csld)
{
  extern __shared__ char lds[];
  constexpr int NT = KDIM / 64;

  // bijective XCD-aware swizzle (nwg % 8 == 0 for all our launches)
  const int gx = gridDim.x, gy = gridDim.y;
  const int nwg = gx * gy * gridDim.z;
  const int hid = blockIdx.x + gx * (blockIdx.y + gy * blockIdx.z);
  const int logical = (hid & 7) * (nwg >> 3) + (hid >> 3);
  const int bx = logical % gx;
  const int rem0 = logical / gx;
  const int by = rem0 % gy;
  const int bz = rem0 / gy;

  const int tid = threadIdx.x;
  const int lane = tid & 63;
  const int wid = tid >> 6;
  const int wr = wid >> 2;   // 0..1
  const int wc = wid & 3;    // 0..3

  const int row0 = by * 256;
  const int col0 = bx * 256;

  const u16* Ab = A + (long long)bz * sAb;
  const u16* Bb = Bt + (long long)bz * sBb;

  // staging sources: instr c (0..3) covers slots idx = c*512 + tid of its
  // operand; ks = c>>1; r = (idx&1023)>>2; cL = idx&3;
  // source k-chunk q = ks*4 + (cL ^ ((r>>1)&3))  [within-row permute]
  const u16* srcA[4]; const u16* srcB[4];
#pragma unroll
  for (int c = 0; c < 4; ++c) {
    int idx = c * 512 + tid;
    int ks = idx >> 10;
    int r = (idx & 1023) >> 2;
    int cL = idx & 3;
    int q = ks * 4 + (cL ^ ((r >> 1) & 3));
    srcA[c] = Ab + (long long)(row0 + r) * KDIM + q * 8;
    srcB[c] = Bb + (long long)(col0 + r) * KDIM + q * 8;
  }

  // stage one ks-half (2 gloads) of A or B into dbuf `buf`
  auto stageA = [&](int buf, int k0, int c0) {
#pragma unroll
    for (int c = c0; c < c0 + 2; ++c)
      gload_lds16(srcA[c] + k0, lds + buf * 32768 + (c * 512 + wid * 64) * 16);
  };
  auto stageB = [&](int buf, int k0, int c0) {
#pragma unroll
    for (int c = c0; c < c0 + 2; ++c)
      gload_lds16(srcB[c] + k0, lds + 65536 + buf * 32768 + (c * 512 + wid * 64) * 16);
  };

  const int p15 = lane & 15;
  const int hi = lane >> 4;

  auto ldA = [&](int buf, int ks, int m) -> f16x8 {
    int r = wr * 128 + m * 16 + p15;
    int cw = hi ^ ((r >> 1) & 3);
    return *(const f16x8*)(lds + buf * 32768 + ks * 16384 + r * 64 + cw * 16);
  };
  auto ldB = [&](int buf, int ks, int n) -> f16x8 {
    int r = wc * 64 + n * 16 + p15;
    int cw = hi ^ ((r >> 1) & 3);
    return *(const f16x8*)(lds + 65536 + buf * 32768 + ks * 16384 + r * 64 + cw * 16);
  };

  f32x4 acc[8][4] = {};
  f16x8 af[4], bf[4];

  // prologue: stage tile 0 fully, ks0 halves first
  stageA(0, 0, 0); stageB(0, 0, 0);   // A-ks0, B-ks0   (oldest 4)
  stageA(0, 0, 2); stageB(0, 0, 2);   // A-ks1, B-ks1
  WAIT_VM(4);                          // tile0 ks0 landed (own); barrier covers all
  BARRIER();

  for (int t = 0; t < NT; ++t) {
    const int buf = t & 1;
    const bool pf = (t + 1 < NT);
    const int nk = (t + 1) * 64;

    // ---- P0: ks0, m0-3 ----
#pragma unroll
    for (int m = 0; m < 4; ++m) af[m] = ldA(buf, 0, m);
#pragma unroll
    for (int n = 0; n < 4; ++n) bf[n] = ldB(buf, 0, n);
    if (pf) stageA(buf ^ 1, nk, 0);
    BARRIER();
    WAIT_LGKM0();
    __builtin_amdgcn_s_setprio(1);
#pragma unroll
    for (int m = 0; m < 4; ++m)
#pragma unroll
      for (int n = 0; n < 4; ++n)
        acc[m][n] = __builtin_amdgcn_mfma_f32_16x16x32_f16(af[m], bf[n], acc[m][n], 0, 0, 0);
    __builtin_amdgcn_s_setprio(0);
    BARRIER();
    // ---- P1: ks0, m4-7 (reuses bf) ----
#pragma unroll
    for (int m = 0; m < 4; ++m) af[m] = ldA(buf, 0, 4 + m);
    if (pf) stageB(buf ^ 1, nk, 0);
    BARRIER();
    WAIT_LGKM0();
    __builtin_amdgcn_s_setprio(1);
#pragma unroll
    for (int m = 0; m < 4; ++m)
#pragma unroll
      for (int n = 0; n < 4; ++n)
        acc[4 + m][n] = __builtin_amdgcn_mfma_f32_16x16x32_f16(af[m], bf[n], acc[4 + m][n], 0, 0, 0);
    __builtin_amdgcn_s_setprio(0);
    // this tile's ks1 (4 oldest outstanding) must have landed
    if (pf) { WAIT_VM(4); } else { WAIT_VM(0); }
    BARRIER();
    // ---- P2: ks1, m0-3 ----
#pragma unroll
    for (int m = 0; m < 4; ++m) af[m] = ldA(buf, 1, m);
#pragma unroll
    for (int n = 0; n < 4; ++n) bf[n] = ldB(buf, 1, n);
    if (pf) stageA(buf ^ 1, nk, 2);
    BARRIER();
    WAIT_LGKM0();
    __builtin_amdgcn_s_setprio(1);
#pragma unroll
    for (int m = 0; m < 4; ++m)
#pragma unroll
      for (int n = 0; n < 4; ++n)
        acc[m][n] = __builtin_amdgcn_mfma_f32_16x16x32_f16(af[m], bf[n], acc[m][n], 0, 0, 0);
    __builtin_amdgcn_s_setprio(0);
    BARRIER();
    // ---- P3: ks1, m4-7 ----
#pragma unroll
    for (int m = 0; m < 4; ++m) af[m] = ldA(buf, 1, 4 + m);
    if (pf) stageB(buf ^ 1, nk, 2);
    BARRIER();
    WAIT_LGKM0();
    __builtin_amdgcn_s_setprio(1);
#pragma unroll
    for (int m = 0; m < 4; ++m)
#pragma unroll
      for (int n = 0; n < 4; ++n)
        acc[4 + m][n] = __builtin_amdgcn_mfma_f32_16x16x32_f16(af[m], bf[n], acc[4 + m][n], 0, 0, 0);
    __builtin_amdgcn_s_setprio(0);
    // next tile's ks0 (4 oldest of the 8 outstanding) must have landed
    if (pf) { WAIT_VM(4); }
    BARRIER();
  }

  __syncthreads();   // full drain; LDS free for epilogue reuse

  // C/D frag layout: col = lane&15, row = (lane>>4)*4 + j
  const int rr = (lane >> 4) * 4;
  const int cc = lane & 15;
  const int grow = row0 + wr * 128;
  const int gcol = col0 + wc * 64;

  if constexpr (EPI == 0 || EPI == 1) {
    // stage u16 128x64 wave-tile in LDS (16 KiB/wave), coalesced dwordx4 out
    char* wb = lds + wid * 16384;
    float csum[4] = {0.f, 0.f, 0.f, 0.f};
#pragma unroll
    for (int m = 0; m < 8; ++m)
#pragma unroll
      for (int n = 0; n < 4; ++n)
#pragma unroll
        for (int j = 0; j < 4; ++j) {
          float x = acc[m][n][j];
          float v;
          if constexpr (EPI == 1) {
            float s = 1.f / (1.f + __expf(-x));   // sigmoid
            v = __expf(s);                        // in (1, e)
            csum[n] += v;
          } else {
            v = x;
          }
          int rl = m * 16 + rr + j;              // 0..127
          int col = n * 16 + cc;                 // 0..63
          int chunk = (col >> 3) ^ (rl & 7);     // bank swizzle
          *(u16*)(wb + rl * 128 + chunk * 16 + ((col * 2) & 15)) = f2h(v);
        }
    if constexpr (EPI == 1) {
#pragma unroll
      for (int n = 0; n < 4; ++n) {
        float v = csum[n];
        v += __shfl_xor(v, 16, 64);
        v += __shfl_xor(v, 32, 64);
        if ((lane >> 4) == 0)
          atomicAdd(&colsum[(long long)bz * csld + gcol + n * 16 + cc], v);
      }
    }
    __syncthreads();   // cross-lane LDS write->read ordering (r6 fix)
    u16* C = (u16*)Cp + (long long)bz * sCb;
#pragma unroll
    for (int s = 0; s < 16; ++s) {
      int rl = (lane >> 3) + s * 8;              // 0..127
      int chunk = (lane & 7) ^ (rl & 7);
      f16x8 v = *(const f16x8*)(wb + rl * 128 + chunk * 16);
      *(f16x8*)(&C[(long long)(grow + rl) * Ndim + gcol + (lane & 7) * 8]) = v;
    }
  } else {
    // f32 out: two 64-row passes, 16 KiB/wave each, coalesced dwordx4
    float* C = (float*)Cp + (long long)bz * sCb;
    char* wb = lds + wid * 16384;
#pragma unroll
    for (int h = 0; h < 2; ++h) {
      if (h) __syncthreads();                    // pass-0 reads done before overwrite
#pragma unroll
      for (int mm = 0; mm < 4; ++mm) {
        int m = h * 4 + mm;
#pragma unroll
        for (int n = 0; n < 4; ++n)
#pragma unroll
          for (int j = 0; j < 4; ++j) {
            int rl = mm * 16 + rr + j;           // 0..63
            int col = n * 16 + cc;               // 0..63
            int chunk = (col >> 2) ^ (rl & 15);  // 16 chunks/row
            *(float*)(wb + rl * 256 + chunk * 16 + ((col * 4) & 15)) =
                acc[m][n][j] * (1.0f / 2048.0f);
          }
      }
      __syncthreads();                           // write->read ordering
#pragma unroll
      for (int s = 0; s < 16; ++s) {
        int rl = (lane >> 4) + s * 4;            // 0..63
        int chunk = (lane & 15) ^ (rl & 15);
        f32x4 v = *(const f32x4*)(wb + rl * 256 + chunk * 16);
        *(f32x4*)(&C[(long long)(grow + h * 64 + rl) * Ndim + gcol + (lane & 15) * 4]) = v;
      }
    }
  }
}

// ---------- launch ----------
// ws layout (bytes):
//   S      @ 0          : 16*2048*2048*2 = 134217728
//   zM     @ 134217728  : 16*2048*512*2  =  33554432
//   zH/eT  @ 167772160  :                  33554432   (z fp16; reused as eT)
//   eH     @ 201326592  :                  33554432
//   Mt     @ 234881024  :                    524288
//   colsum @ 235405312  : 16*2048*4      =    131072
extern "C" void kernel_launch(void* const* d_in, const int* in_sizes, int n_in,
                              void* d_out, int out_size, void* d_ws, size_t ws_size,
                              hipStream_t stream) {
  const float* z = (const float*)d_in[0];
  const float* e = (const float*)d_in[1];
  const float* M = (const float*)d_in[2];
  float* out = (float*)d_out;
  char* ws = (char*)d_ws;

  u16* S    = (u16*)(ws + 0LL);
  u16* zM   = (u16*)(ws + 134217728LL);
  u16* zH   = (u16*)(ws + 167772160LL);
  u16* eH   = (u16*)(ws + 201326592LL);
  u16* Mt   = (u16*)(ws + 234881024LL);
  float* cs = (float*)(ws + 235405312LL);

  (void)hipFuncSetAttribute(reinterpret_cast<const void*>(&k_gemm<0, 512>),
                            hipFuncAttributeMaxDynamicSharedMemorySize, 131072);
  (void)hipFuncSetAttribute(reinterpret_cast<const void*>(&k_gemm<1, 512>),
                            hipFuncAttributeMaxDynamicSharedMemorySize, 131072);
  (void)hipFuncSetAttribute(reinterpret_cast<const void*>(&k_gemm<2, 2048>),
                            hipFuncAttributeMaxDynamicSharedMemorySize, 131072);

  hipMemsetAsync(cs, 0, (size_t)BB * NE * sizeof(float), stream);

  k_cvt<<<4096, 256, 0, stream>>>(z, zH, BB * NZ * DD / 4);
  k_cvt<<<4096, 256, 0, stream>>>(e, eH, BB * NE * DD / 4);
  k_mt<<<dim3(16, 16), dim3(32, 8), 0, stream>>>(M, Mt);

  // zM[32768 x 512] = zH @ Mt^T   (batch folded into rows); 256 blocks
  k_gemm<0, 512><<<dim3(DD / 256, (BB * NZ) / 256, 1), 512, 131072, stream>>>(
      zH, Mt, zM, DD, 0LL, 0LL, 0LL, nullptr, 0);

  // S[b] = exp(sigmoid(zM[b] @ eH[b]^T)) ; colsum atomics; 1024 blocks
  k_gemm<1, 512><<<dim3(NE / 256, NZ / 256, BB), 512, 131072, stream>>>(
      zM, eH, S, NE,
      (long long)NZ * DD, (long long)NE * DD, (long long)NZ * NE, cs, NE);

  // eT'[b][d][m] = fp16(eH[b][m][d] * 2048 / colsum[b][m])   (reuses zH region)
  u16* eT = zH;
  k_et<<<dim3(DD / 32, NE / 32, BB), dim3(32, 8), 0, stream>>>(eH, cs, eT);

  // out[b] = (S[b] @ eT[b]^T) / 2048 ; 256 blocks
  k_gemm<2, 2048><<<dim3(DD / 256, NZ / 256, BB), 512, 131072, stream>>>(
      S, eT, out, DD,
      (long long)NZ * NE, (long long)DD * NE, (long long)NZ * DD, nullptr, 0);
}

// Round 16
// 277.553 us; speedup vs baseline: 1.2897x; 1.0017x over previous
//
#include <hip/hip_runtime.h>
#include <hip/hip_bf16.h>
#include <stdint.h>

#define BB 16
#define NZ 2048
#define NE 2048
#define DD 512

typedef unsigned short u16;
typedef __attribute__((ext_vector_type(8))) _Float16 f16x8;  // 8 fp16 = 4 VGPR
typedef __attribute__((ext_vector_type(8))) short s16x8;
typedef __attribute__((ext_vector_type(4))) float f32x4;

// ---------- helpers ----------
__device__ __forceinline__ u16 f2h(float f) {
  _Float16 h = (_Float16)f;                 // v_cvt_f16_f32, RNE
  return __builtin_bit_cast(u16, h);
}

__device__ __forceinline__ float h2f(u16 h) {
  return (float)__builtin_bit_cast(_Float16, h);
}

__device__ __forceinline__ void gload_lds16(const void* g, void* l) {
  auto gp = (const __attribute__((address_space(1))) uint32_t*)g;
  auto lp = (__attribute__((address_space(3))) uint32_t*)l;
  __builtin_amdgcn_global_load_lds(gp, lp, 16, 0, 0);
}

#define FENCE() asm volatile("" ::: "memory")
#define BARRIER() do { FENCE(); __builtin_amdgcn_s_barrier(); FENCE(); } while (0)
#define WAIT_VM(n) asm volatile("s_waitcnt vmcnt(" #n ")" ::: "memory")

// ---------- f32 -> fp16 bulk convert (16B stores) ----------
__global__ void k_cvt(const float* __restrict__ in, u16* __restrict__ out, int n8) {
  int i = blockIdx.x * blockDim.x + threadIdx.x;
  int stride = gridDim.x * blockDim.x;
  for (; i < n8; i += stride) {
    float4 v0 = ((const float4*)in)[i * 2];
    float4 v1 = ((const float4*)in)[i * 2 + 1];
    s16x8 o;
    o[0] = (short)f2h(v0.x); o[1] = (short)f2h(v0.y);
    o[2] = (short)f2h(v0.z); o[3] = (short)f2h(v0.w);
    o[4] = (short)f2h(v1.x); o[5] = (short)f2h(v1.y);
    o[6] = (short)f2h(v1.z); o[7] = (short)f2h(v1.w);
    ((s16x8*)out)[i] = o;
  }
}

// ---------- M[512x512] -> Mt fp16 (Mt[e][d] = M[d][e]) ----------
__global__ void k_mt(const float* __restrict__ M, u16* __restrict__ Mt) {
  __shared__ float t[32][33];
  int bx = blockIdx.x * 32;  // e range
  int by = blockIdx.y * 32;  // d range
  for (int r = 0; r < 32; r += 8)
    t[threadIdx.y + r][threadIdx.x] = M[(size_t)(by + threadIdx.y + r) * DD + bx + threadIdx.x];
  __syncthreads();
  for (int r = 0; r < 32; r += 8)
    Mt[(size_t)(bx + threadIdx.y + r) * DD + by + threadIdx.x] = f2h(t[threadIdx.x][threadIdx.y + r]);
}

// ---------- k_et: eT'[b][d][m] = fp16( eH[b][m][d] * 2048 / cs[b][m] ) --------
// 64x64 tile, fully 16B-vectorized both sides (old version was 2B/lane).
// LDS u16[64][72] (stride 144B, 16B-aligned); logical col m stored at
// 8-block (ml>>3) ^ (d&7)  -> write banks all-32 distinct, read stays
// 16B-contiguous.  [derivation in round notes]
__global__ void k_et(const u16* __restrict__ eH, const float* __restrict__ cs,
                     u16* __restrict__ eT) {
  __shared__ u16 sm[64 * 72];
  const int t = threadIdx.x;
  const int b = blockIdx.z;
  const int d0 = blockIdx.x * 64;
  const int m0 = blockIdx.y * 64;
  const u16* eb = eH + (size_t)b * NE * DD;
  const float* csb = cs + (size_t)b * NE;
#pragma unroll
  for (int it = 0; it < 2; ++it) {
    int idx = it * 256 + t;           // 0..511
    int ml = idx >> 3;                // 0..63
    int dc = idx & 7;                 // 8-d chunk
    s16x8 v = *(const s16x8*)(eb + (size_t)(m0 + ml) * DD + d0 + dc * 8);
    float sc = 2048.0f / csb[m0 + ml];
    int bl = ml >> 3, il = ml & 7;
#pragma unroll
    for (int j = 0; j < 8; ++j) {
      int d = dc * 8 + j;             // d&7 == j
      int pc = ((bl ^ j) << 3) + il;  // permuted col
      sm[d * 72 + pc] = f2h(h2f((u16)v[j]) * sc);
    }
  }
  __syncthreads();
  u16* eTb = eT + (size_t)b * DD * NE;
#pragma unroll
  for (int it = 0; it < 2; ++it) {
    int idx = it * 256 + t;
    int dl = idx >> 3;                // 0..63
    int mc = idx & 7;                 // 8-m chunk
    int pb = mc ^ (dl & 7);           // permuted block
    s16x8 v = *(const s16x8*)&sm[dl * 72 + pb * 8];
    *(s16x8*)(eTb + (size_t)(d0 + dl) * NE + m0 + mc * 8) = v;
  }
}

// ---------- 128x128 tile, BK=32, 4-wave, 3-slot ring, 3 blocks/CU ----------
// C = A[M x K] * Bt[N x K]^T.  256 threads = 4 waves (2M x 2N), per-wave 64x64.
// LDS 48 KiB = 3 ring slots x 16 KiB (A 8K @ +0, B 8K @ +8192), linear 64-B
// rows + XOR chunk swizzle q = cL ^ ((r>>1)&3)  [r10/r11-verified: coalesced
// global_load_lds AND conflict-free ds_read_b128].  48 KiB + launch_bounds
// (256,3) => 3 resident blocks/CU (r10's occupancy winner) WITH r11's
// counted-vmcnt 2-step-deep prefetch (never combined before).
// Step t: read slot t%3 (8 ds_read) + 16 MFMA; BAR#1 [reads done];
// stage(t+2) -> slot (t+2)%3 [WAR-safe: last read step t-1, BAR#1 between];
// WAIT_VM(4) [tile t+1 drained, t+2 in flight; 0 only at t=NT-2]; BAR#2
// [tile t+1 visible to ALL waves: each vm-waited BEFORE this barrier].
// EPI: 0 = fp16 out; 1 = exp(sigmoid(x)) fp16 out + colsum atomics; 2 = f32/2048
template<int EPI, int KDIM>
__global__ __launch_bounds__(256, 3) void k_gemm(
    const u16* __restrict__ A, const u16* __restrict__ Bt, void* __restrict__ Cp,
    int Ndim, long long sAb, long long sBb, long long sCb,
    float* __restrict__ colsum, int csld)
{
  extern __shared__ char lds[];
  constexpr int NT = KDIM / 32;

  // bijective XCD-aware swizzle (nwg % 8 == 0 for all our launches)
  const int gx = gridDim.x, gy = gridDim.y;
  const int nwg = gx * gy * gridDim.z;
  const int hid = blockIdx.x + gx * (blockIdx.y + gy * blockIdx.z);
  const int logical = (hid & 7) * (nwg >> 3) + (hid >> 3);
  const int bx = logical % gx;
  const int rem0 = logical / gx;
  const int by = rem0 % gy;
  const int bz = rem0 / gy;

  const int tid = threadIdx.x;
  const int lane = tid & 63;
  const int wid = tid >> 6;
  const int wr = wid >> 1;   // 0..1
  const int wc = wid & 1;    // 0..1

  const int row0 = by * 128;
  const int col0 = bx * 128;

  const u16* Ab = A + (long long)bz * sAb;
  const u16* Bb = Bt + (long long)bz * sBb;

  // staging sources (linear dest, XOR-permuted source chunk within the row):
  // instr c covers LDS slots idx = c*256 + tid;  r = idx>>2, cL = idx&3,
  // source chunk q = cL ^ ((r>>1)&3)  (stays inside row r's 64B -> coalesced)
  const u16* srcA[2]; const u16* srcB[2];
#pragma unroll
  for (int c = 0; c < 2; ++c) {
    int idx = c * 256 + tid;
    int r = idx >> 2;
    int cL = idx & 3;
    int q = cL ^ ((r >> 1) & 3);
    srcA[c] = Ab + (long long)(row0 + r) * KDIM + q * 8;
    srcB[c] = Bb + (long long)(col0 + r) * KDIM + q * 8;
  }

  auto stage = [&](int t) {
    const int k0 = t * 32;
    char* d = lds + (t % 3) * 16384;
#pragma unroll
    for (int c = 0; c < 2; ++c)
      gload_lds16(srcA[c] + k0, d + (c * 256 + wid * 64) * 16);
#pragma unroll
    for (int c = 0; c < 2; ++c)
      gload_lds16(srcB[c] + k0, d + 8192 + (c * 256 + wid * 64) * 16);
  };

  const int p15 = lane & 15;
  const int cswz = (lane >> 4) ^ ((p15 >> 1) & 3);  // note: depends on r too; folded below

  f32x4 acc[4][4] = {};

  stage(0);
  stage(1);
  WAIT_VM(4);        // tile0 drained (own); barrier makes it visible to all
  BARRIER();

  for (int t = 0; t < NT; ++t) {
    char* lA = lds + (t % 3) * 16384;
    char* lB = lA + 8192;

    f16x8 af[4], bf[4];
#pragma unroll
    for (int m = 0; m < 4; ++m) {
      int r = wr * 64 + m * 16 + p15;
      int c4 = (lane >> 4) ^ ((r >> 1) & 3);
      af[m] = *(const f16x8*)(lA + r * 64 + c4 * 16);
    }
#pragma unroll
    for (int n = 0; n < 4; ++n) {
      int r = wc * 64 + n * 16 + p15;
      int c4 = (lane >> 4) ^ ((r >> 1) & 3);
      bf[n] = *(const f16x8*)(lB + r * 64 + c4 * 16);
    }
#pragma unroll
    for (int m = 0; m < 4; ++m)
#pragma unroll
      for (int n = 0; n < 4; ++n)
        acc[m][n] = __builtin_amdgcn_mfma_f32_16x16x32_f16(af[m], bf[n], acc[m][n], 0, 0, 0);

    BARRIER();                        // #1: all waves' reads of slots <= t done
    if (t + 2 < NT) stage(t + 2);     // WAR-safe (last read step t-1, bar above)
    if (t + 1 < NT) {
      if (t + 2 < NT) { WAIT_VM(4); } else { WAIT_VM(0); }   // drain tile t+1
      BARRIER();                      // #2: tile t+1 visible to all waves
    }
  }

  __syncthreads();   // full drain; LDS free for epilogue reuse

  // C/D frag layout: col = lane&15, row = (lane>>4)*4 + j
  const int rr = (lane >> 4) * 4;
  const int cc = lane & 15;
  const int grow = row0 + wr * 64;
  const int gcol = col0 + wc * 64;
  (void)cswz;

  if constexpr (EPI == 0 || EPI == 1) {
    // stage u16 64x64 wave-tile in LDS (8 KiB/wave), then coalesced dwordx4
    char* wb = lds + wid * 8192;
    float csum[4] = {0.f, 0.f, 0.f, 0.f};
#pragma unroll
    for (int m = 0; m < 4; ++m)
#pragma unroll
      for (int n = 0; n < 4; ++n)
#pragma unroll
        for (int j = 0; j < 4; ++j) {
          float x = acc[m][n][j];
          float v;
          if constexpr (EPI == 1) {
            float s = 1.f / (1.f + __expf(-x));   // sigmoid
            v = __expf(s);                        // in (1, e)
            csum[n] += v;
          } else {
            v = x;
          }
          int rl = m * 16 + rr + j;              // 0..63
          int col = n * 16 + cc;                 // 0..63
          int chunk = (col >> 3) ^ (rl & 7);     // bank swizzle
          *(u16*)(wb + rl * 128 + chunk * 16 + ((col * 2) & 15)) = f2h(v);
        }
    if constexpr (EPI == 1) {
#pragma unroll
      for (int n = 0; n < 4; ++n) {
        float v = csum[n];
        v += __shfl_xor(v, 16, 64);
        v += __shfl_xor(v, 32, 64);
        if ((lane >> 4) == 0)
          atomicAdd(&colsum[(long long)bz * csld + gcol + n * 16 + cc], v);
      }
    }
    __syncthreads();   // cross-lane LDS write->read ordering (r6 fix)
    u16* C = (u16*)Cp + (long long)bz * sCb;
#pragma unroll
    for (int s = 0; s < 8; ++s) {
      int rl = (lane >> 3) + s * 8;
      int chunk = (lane & 7) ^ (rl & 7);
      f16x8 v = *(const f16x8*)(wb + rl * 128 + chunk * 16);
      *(f16x8*)(&C[(long long)(grow + rl) * Ndim + gcol + (lane & 7) * 8]) = v;
    }
  } else {
    // f32 out: two 32-row passes, 8 KiB/wave each, coalesced dwordx4
    float* C = (float*)Cp + (long long)bz * sCb;
    char* wb = lds + wid * 8192;
#pragma unroll
    for (int h = 0; h < 2; ++h) {
      if (h) __syncthreads();                    // pass-0 reads done before overwrite
#pragma unroll
      for (int mm = 0; mm < 2; ++mm) {
        int m = h * 2 + mm;
#pragma unroll
        for (int n = 0; n < 4; ++n)
#pragma unroll
          for (int j = 0; j < 4; ++j) {
            int rl = mm * 16 + rr + j;           // 0..31
            int col = n * 16 + cc;               // 0..63
            int chunk = (col >> 2) ^ (rl & 15);  // 16 chunks/row
            *(float*)(wb + rl * 256 + chunk * 16 + ((col * 4) & 15)) =
                acc[m][n][j] * (1.0f / 2048.0f);
          }
      }
      __syncthreads();                           // write->read ordering
#pragma unroll
      for (int s = 0; s < 8; ++s) {
        int rl = (lane >> 4) + s * 4;            // 0..31
        int chunk = (lane & 15) ^ (rl & 15);
        f32x4 v = *(const f32x4*)(wb + rl * 256 + chunk * 16);
        *(f32x4*)(&C[(long long)(grow + h * 32 + rl) * Ndim + gcol + (lane & 15) * 4]) = v;
      }
    }
  }
}

// ---------- launch ----------
// ws layout (bytes):
//   S      @ 0          : 16*2048*2048*2 = 134217728
//   zM     @ 134217728  : 16*2048*512*2  =  33554432
//   zH/eT  @ 167772160  :                  33554432   (z fp16; reused as eT)
//   eH     @ 201326592  :                  33554432
//   Mt     @ 234881024  :                    524288
//   colsum @ 235405312  : 16*2048*4      =    131072
extern "C" void kernel_launch(void* const* d_in, const int* in_sizes, int n_in,
                              void* d_out, int out_size, void* d_ws, size_t ws_size,
                              hipStream_t stream) {
  const float* z = (const float*)d_in[0];
  const float* e = (const float*)d_in[1];
  const float* M = (const float*)d_in[2];
  float* out = (float*)d_out;
  char* ws = (char*)d_ws;

  u16* S    = (u16*)(ws + 0LL);
  u16* zM   = (u16*)(ws + 134217728LL);
  u16* zH   = (u16*)(ws + 167772160LL);
  u16* eH   = (u16*)(ws + 201326592LL);
  u16* Mt   = (u16*)(ws + 234881024LL);
  float* cs = (float*)(ws + 235405312LL);

  hipMemsetAsync(cs, 0, (size_t)BB * NE * sizeof(float), stream);

  k_cvt<<<4096, 256, 0, stream>>>(z, zH, BB * NZ * DD / 8);
  k_cvt<<<4096, 256, 0, stream>>>(e, eH, BB * NE * DD / 8);
  k_mt<<<dim3(16, 16), dim3(32, 8), 0, stream>>>(M, Mt);

  // zM[32768 x 512] = zH @ Mt^T   (batch folded into rows); 1024 blocks
  k_gemm<0, 512><<<dim3(DD / 128, (BB * NZ) / 128, 1), 256, 49152, stream>>>(
      zH, Mt, zM, DD, 0LL, 0LL, 0LL, nullptr, 0);

  // S[b] = exp(sigmoid(zM[b] @ eH[b]^T)) ; colsum atomics; 4096 blocks
  k_gemm<1, 512><<<dim3(NE / 128, NZ / 128, BB), 256, 49152, stream>>>(
      zM, eH, S, NE,
      (long long)NZ * DD, (long long)NE * DD, (long long)NZ * NE, cs, NE);

  // eT'[b][d][m] = fp16(eH[b][m][d] * 2048 / colsum[b][m])   (reuses zH region)
  u16* eT = zH;
  k_et<<<dim3(DD / 64, NE / 64, BB), 256, 0, stream>>>(eH, cs, eT);

  // out[b] = (S[b] @ eT[b]^T) / 2048 ; 1024 blocks
  k_gemm<2, 2048><<<dim3(DD / 128, NZ / 128, BB), 256, 49152, stream>>>(
      S, eT, out, DD,
      (long long)NZ * NE, (long long)DD * NE, (long long)NZ * DD, nullptr, 0);
}

// Round 18
// 276.682 us; speedup vs baseline: 1.2937x; 1.0031x over previous
//
#include <hip/hip_runtime.h>
#include <hip/hip_bf16.h>
#include <stdint.h>

#define BB 16
#define NZ 2048
#define NE 2048
#define DD 512

typedef unsigned short u16;
typedef __attribute__((ext_vector_type(8))) _Float16 f16x8;  // 8 fp16 = 4 VGPR
typedef __attribute__((ext_vector_type(8))) short s16x8;
typedef __attribute__((ext_vector_type(4))) float f32x4;

// ---------- helpers ----------
__device__ __forceinline__ u16 f2h(float f) {
  _Float16 h = (_Float16)f;                 // v_cvt_f16_f32, RNE
  return __builtin_bit_cast(u16, h);
}

__device__ __forceinline__ float h2f(u16 h) {
  return (float)__builtin_bit_cast(_Float16, h);
}

__device__ __forceinline__ void gload_lds16(const void* g, void* l) {
  auto gp = (const __attribute__((address_space(1))) uint32_t*)g;
  auto lp = (__attribute__((address_space(3))) uint32_t*)l;
  __builtin_amdgcn_global_load_lds(gp, lp, 16, 0, 0);
}

#define FENCE() asm volatile("" ::: "memory")
#define BARRIER() do { FENCE(); __builtin_amdgcn_s_barrier(); FENCE(); } while (0)
#define WAIT_LGKM0() asm volatile("s_waitcnt lgkmcnt(0)" ::: "memory")
#define WAIT_VM(n) asm volatile("s_waitcnt vmcnt(" #n ")" ::: "memory")

// ---------- f32 -> fp16 bulk convert (16B stores) ----------
__global__ void k_cvt(const float* __restrict__ in, u16* __restrict__ out, int n8) {
  int i = blockIdx.x * blockDim.x + threadIdx.x;
  int stride = gridDim.x * blockDim.x;
  for (; i < n8; i += stride) {
    float4 v0 = ((const float4*)in)[i * 2];
    float4 v1 = ((const float4*)in)[i * 2 + 1];
    s16x8 o;
    o[0] = (short)f2h(v0.x); o[1] = (short)f2h(v0.y);
    o[2] = (short)f2h(v0.z); o[3] = (short)f2h(v0.w);
    o[4] = (short)f2h(v1.x); o[5] = (short)f2h(v1.y);
    o[6] = (short)f2h(v1.z); o[7] = (short)f2h(v1.w);
    ((s16x8*)out)[i] = o;
  }
}

// ---------- M[512x512] -> Mt fp16 (Mt[e][d] = M[d][e]) ----------
__global__ void k_mt(const float* __restrict__ M, u16* __restrict__ Mt) {
  __shared__ float t[32][33];
  int bx = blockIdx.x * 32;  // e range
  int by = blockIdx.y * 32;  // d range
  for (int r = 0; r < 32; r += 8)
    t[threadIdx.y + r][threadIdx.x] = M[(size_t)(by + threadIdx.y + r) * DD + bx + threadIdx.x];
  __syncthreads();
  for (int r = 0; r < 32; r += 8)
    Mt[(size_t)(bx + threadIdx.y + r) * DD + by + threadIdx.x] = f2h(t[threadIdx.x][threadIdx.y + r]);
}

// ---------- k_et: eT'[b][d][m] = fp16( eH[b][m][d] * 2048 / cs[b][m] ) --------
// 64x64 tile, fully 16B-vectorized both sides; XOR-block-permuted LDS
// (r16-verified).
__global__ void k_et(const u16* __restrict__ eH, const float* __restrict__ cs,
                     u16* __restrict__ eT) {
  __shared__ u16 sm[64 * 72];
  const int t = threadIdx.x;
  const int b = blockIdx.z;
  const int d0 = blockIdx.x * 64;
  const int m0 = blockIdx.y * 64;
  const u16* eb = eH + (size_t)b * NE * DD;
  const float* csb = cs + (size_t)b * NE;
#pragma unroll
  for (int it = 0; it < 2; ++it) {
    int idx = it * 256 + t;           // 0..511
    int ml = idx >> 3;                // 0..63
    int dc = idx & 7;                 // 8-d chunk
    s16x8 v = *(const s16x8*)(eb + (size_t)(m0 + ml) * DD + d0 + dc * 8);
    float sc = 2048.0f / csb[m0 + ml];
    int bl = ml >> 3, il = ml & 7;
#pragma unroll
    for (int j = 0; j < 8; ++j) {
      int d = dc * 8 + j;             // d&7 == j
      int pc = ((bl ^ j) << 3) + il;  // permuted col
      sm[d * 72 + pc] = f2h(h2f((u16)v[j]) * sc);
    }
  }
  __syncthreads();
  u16* eTb = eT + (size_t)b * DD * NE;
#pragma unroll
  for (int it = 0; it < 2; ++it) {
    int idx = it * 256 + t;
    int dl = idx >> 3;                // 0..63
    int mc = idx & 7;                 // 8-m chunk
    int pb = mc ^ (dl & 7);           // permuted block
    s16x8 v = *(const s16x8*)&sm[dl * 72 + pb * 8];
    *(s16x8*)(eTb + (size_t)(d0 + dl) * NE + m0 + mc * 8) = v;
  }
}

// ---------- 128x128 tile, BK=32, 4-wave, 3-slot ring, 3 blocks/CU ----------
// r16's verified TWO-barrier ledger + r17's de-VALU addressing (r18):
//  * fragment swizzle c4 = (lane>>4) ^ ((p15>>1)&3) is m/n/wave-invariant
//    (((w*64+m*16+p15)>>1)&3 == (p15>>1)&3) -> ONE per-lane byte offset per
//    operand; all 8 ds_reads = base + compile-time imm.
//  * 3 rotating slot pointers (no t%3); 4 running staging source pointers.
// Step t: read slot sl0 (8 ds_read) + 16 MFMA; lgkmcnt(0) [reads COMPLETE];
// BAR#1; stage(t+2) -> sl2 [WAR-safe: slot last read step t-1, two barriers
// + full MFMA phase ago]; WAIT_VM(4) [tile t+1 drained; 0 only at t=NT-2];
// BAR#2 [tile t+1 visible to all waves]; rotate slots.
// r17's single-barrier variant RACED (absmax 3.5e-2): one barrier between a
// slot's last read and overwrite is unsafe if lgkm completion sinks past it.
// EPI: 0 = fp16 out; 1 = exp(sigmoid(x)) fp16 out + colsum atomics; 2 = f32/2048
template<int EPI, int KDIM>
__global__ __launch_bounds__(256, 3) void k_gemm(
    const u16* __restrict__ A, const u16* __restrict__ Bt, void* __restrict__ Cp,
    int Ndim, long long sAb, long long sBb, long long sCb,
    float* __restrict__ colsum, int csld)
{
  extern __shared__ char lds[];
  constexpr int NT = KDIM / 32;

  // bijective XCD-aware swizzle (nwg % 8 == 0 for all our launches)
  const int gx = gridDim.x, gy = gridDim.y;
  const int nwg = gx * gy * gridDim.z;
  const int hid = blockIdx.x + gx * (blockIdx.y + gy * blockIdx.z);
  const int logical = (hid & 7) * (nwg >> 3) + (hid >> 3);
  const int bx = logical % gx;
  const int rem0 = logical / gx;
  const int by = rem0 % gy;
  const int bz = rem0 / gy;

  const int tid = threadIdx.x;
  const int lane = tid & 63;
  const int wid = tid >> 6;
  const int wr = wid >> 1;   // 0..1
  const int wc = wid & 1;    // 0..1

  const int row0 = by * 128;
  const int col0 = bx * 128;

  const u16* Ab = A + (long long)bz * sAb;
  const u16* Bb = Bt + (long long)bz * sBb;

  // staging sources (linear dest, XOR-permuted source chunk within the row):
  // instr c covers LDS slots idx = c*256 + tid;  r = idx>>2, cL = idx&3,
  // source chunk q = cL ^ ((r>>1)&3)  (stays inside row r's 64B -> coalesced)
  const u16* srcA[2]; const u16* srcB[2];
#pragma unroll
  for (int c = 0; c < 2; ++c) {
    int idx = c * 256 + tid;
    int r = idx >> 2;
    int cL = idx & 3;
    int q = cL ^ ((r >> 1) & 3);
    srcA[c] = Ab + (long long)(row0 + r) * KDIM + q * 8;
    srcB[c] = Bb + (long long)(col0 + r) * KDIM + q * 8;
  }

  // per-lane invariant fragment offsets (header proof)
  const int p15 = lane & 15;
  const int c4 = (lane >> 4) ^ ((p15 >> 1) & 3);
  const int laneA = (wr * 64 + p15) * 64 + c4 * 16;          // + m*1024
  const int laneB = 8192 + (wc * 64 + p15) * 64 + c4 * 16;   // + n*1024
  const int dA0 = wid * 1024, dA1 = 4096 + wid * 1024;
  const int dB0 = 8192 + wid * 1024, dB1 = 12288 + wid * 1024;

  f32x4 acc[4][4] = {};

  // rotating slot bases: sl0 = tile t, sl1 = t+1, sl2 = staging target (t+2)
  char* sl0 = lds;
  char* sl1 = lds + 16384;
  char* sl2 = lds + 32768;

  // prologue: tile0 -> slot0, tile1 -> slot1
  gload_lds16(srcA[0], sl0 + dA0);
  gload_lds16(srcA[1], sl0 + dA1);
  gload_lds16(srcB[0], sl0 + dB0);
  gload_lds16(srcB[1], sl0 + dB1);
  gload_lds16(srcA[0] + 32, sl1 + dA0);
  gload_lds16(srcA[1] + 32, sl1 + dA1);
  gload_lds16(srcB[0] + 32, sl1 + dB0);
  gload_lds16(srcB[1] + 32, sl1 + dB1);
  WAIT_VM(4);        // tile0 drained (own loads); barrier makes it visible
  BARRIER();

  // running staging sources, positioned at tile 2
  const u16* pA0 = srcA[0] + 64;
  const u16* pA1 = srcA[1] + 64;
  const u16* pB0 = srcB[0] + 64;
  const u16* pB1 = srcB[1] + 64;

  for (int t = 0; t < NT; ++t) {
    char* baseA = sl0 + laneA;
    char* baseB = sl0 + laneB;
    f16x8 af[4], bf[4];
#pragma unroll
    for (int m = 0; m < 4; ++m) af[m] = *(const f16x8*)(baseA + m * 1024);
#pragma unroll
    for (int n = 0; n < 4; ++n) bf[n] = *(const f16x8*)(baseB + n * 1024);
#pragma unroll
    for (int m = 0; m < 4; ++m)
#pragma unroll
      for (int n = 0; n < 4; ++n)
        acc[m][n] = __builtin_amdgcn_mfma_f32_16x16x32_f16(af[m], bf[n], acc[m][n], 0, 0, 0);

    WAIT_LGKM0();                     // reads of sl0 COMPLETE before barrier
    BARRIER();                        // #1: all waves' reads done
    if (t + 2 < NT) {                 // stage tile t+2 into sl2
      gload_lds16(pA0, sl2 + dA0);    // (slot last read at step t-1: 2 bars ago)
      gload_lds16(pA1, sl2 + dA1);
      gload_lds16(pB0, sl2 + dB0);
      gload_lds16(pB1, sl2 + dB1);
      pA0 += 32; pA1 += 32; pB0 += 32; pB1 += 32;
    }
    if (t + 1 < NT) {
      if (t + 2 < NT) { WAIT_VM(4); } else { WAIT_VM(0); }   // tile t+1 drained
      BARRIER();                       // #2: tile t+1 visible to all waves
    }
    char* tmp = sl0; sl0 = sl1; sl1 = sl2; sl2 = tmp;
  }

  __syncthreads();   // full drain; LDS free for epilogue reuse

  // C/D frag layout: col = lane&15, row = (lane>>4)*4 + j
  const int rr = (lane >> 4) * 4;
  const int cc = lane & 15;
  const int grow = row0 + wr * 64;
  const int gcol = col0 + wc * 64;

  if constexpr (EPI == 0 || EPI == 1) {
    // stage u16 64x64 wave-tile in LDS (8 KiB/wave), then coalesced dwordx4
    char* wb = lds + wid * 8192;
    float csum[4] = {0.f, 0.f, 0.f, 0.f};
#pragma unroll
    for (int m = 0; m < 4; ++m)
#pragma unroll
      for (int n = 0; n < 4; ++n)
#pragma unroll
        for (int j = 0; j < 4; ++j) {
          float x = acc[m][n][j];
          float v;
          if constexpr (EPI == 1) {
            float s = 1.f / (1.f + __expf(-x));   // sigmoid
            v = __expf(s);                        // in (1, e)
            csum[n] += v;
          } else {
            v = x;
          }
          int rl = m * 16 + rr + j;              // 0..63
          int col = n * 16 + cc;                 // 0..63
          int chunk = (col >> 3) ^ (rl & 7);     // bank swizzle
          *(u16*)(wb + rl * 128 + chunk * 16 + ((col * 2) & 15)) = f2h(v);
        }
    if constexpr (EPI == 1) {
#pragma unroll
      for (int n = 0; n < 4; ++n) {
        float v = csum[n];
        v += __shfl_xor(v, 16, 64);
        v += __shfl_xor(v, 32, 64);
        if ((lane >> 4) == 0)
          atomicAdd(&colsum[(long long)bz * csld + gcol + n * 16 + cc], v);
      }
    }
    __syncthreads();   // cross-lane LDS write->read ordering (r6 fix)
    u16* C = (u16*)Cp + (long long)bz * sCb;
#pragma unroll
    for (int s = 0; s < 8; ++s) {
      int rl = (lane >> 3) + s * 8;
      int chunk = (lane & 7) ^ (rl & 7);
      f16x8 v = *(const f16x8*)(wb + rl * 128 + chunk * 16);
      *(f16x8*)(&C[(long long)(grow + rl) * Ndim + gcol + (lane & 7) * 8]) = v;
    }
  } else {
    // f32 out: two 32-row passes, 8 KiB/wave each, coalesced dwordx4
    float* C = (float*)Cp + (long long)bz * sCb;
    char* wb = lds + wid * 8192;
#pragma unroll
    for (int h = 0; h < 2; ++h) {
      if (h) __syncthreads();                    // pass-0 reads done before overwrite
#pragma unroll
      for (int mm = 0; mm < 2; ++mm) {
        int m = h * 2 + mm;
#pragma unroll
        for (int n = 0; n < 4; ++n)
#pragma unroll
          for (int j = 0; j < 4; ++j) {
            int rl = mm * 16 + rr + j;           // 0..31
            int col = n * 16 + cc;               // 0..63
            int chunk = (col >> 2) ^ (rl & 15);  // 16 chunks/row
            *(float*)(wb + rl * 256 + chunk * 16 + ((col * 4) & 15)) =
                acc[m][n][j] * (1.0f / 2048.0f);
          }
      }
      __syncthreads();                           // write->read ordering
#pragma unroll
      for (int s = 0; s < 8; ++s) {
        int rl = (lane >> 4) + s * 4;            // 0..31
        int chunk = (lane & 15) ^ (rl & 15);
        f32x4 v = *(const f32x4*)(wb + rl * 256 + chunk * 16);
        *(f32x4*)(&C[(long long)(grow + h * 32 + rl) * Ndim + gcol + (lane & 15) * 4]) = v;
      }
    }
  }
}

// ---------- launch ----------
// ws layout (bytes):
//   S      @ 0          : 16*2048*2048*2 = 134217728
//   zM     @ 134217728  : 16*2048*512*2  =  33554432
//   zH/eT  @ 167772160  :                  33554432   (z fp16; reused as eT)
//   eH     @ 201326592  :                  33554432
//   Mt     @ 234881024  :                    524288
//   colsum @ 235405312  : 16*2048*4      =    131072
extern "C" void kernel_launch(void* const* d_in, const int* in_sizes, int n_in,
                              void* d_out, int out_size, void* d_ws, size_t ws_size,
                              hipStream_t stream) {
  const float* z = (const float*)d_in[0];
  const float* e = (const float*)d_in[1];
  const float* M = (const float*)d_in[2];
  float* out = (float*)d_out;
  char* ws = (char*)d_ws;

  u16* S    = (u16*)(ws + 0LL);
  u16* zM   = (u16*)(ws + 134217728LL);
  u16* zH   = (u16*)(ws + 167772160LL);
  u16* eH   = (u16*)(ws + 201326592LL);
  u16* Mt   = (u16*)(ws + 234881024LL);
  float* cs = (float*)(ws + 235405312LL);

  hipMemsetAsync(cs, 0, (size_t)BB * NE * sizeof(float), stream);

  k_cvt<<<4096, 256, 0, stream>>>(z, zH, BB * NZ * DD / 8);
  k_cvt<<<4096, 256, 0, stream>>>(e, eH, BB * NE * DD / 8);
  k_mt<<<dim3(16, 16), dim3(32, 8), 0, stream>>>(M, Mt);

  // zM[32768 x 512] = zH @ Mt^T   (batch folded into rows); 1024 blocks
  k_gemm<0, 512><<<dim3(DD / 128, (BB * NZ) / 128, 1), 256, 49152, stream>>>(
      zH, Mt, zM, DD, 0LL, 0LL, 0LL, nullptr, 0);

  // S[b] = exp(sigmoid(zM[b] @ eH[b]^T)) ; colsum atomics; 4096 blocks
  k_gemm<1, 512><<<dim3(NE / 128, NZ / 128, BB), 256, 49152, stream>>>(
      zM, eH, S, NE,
      (long long)NZ * DD, (long long)NE * DD, (long long)NZ * NE, cs, NE);

  // eT'[b][d][m] = fp16(eH[b][m][d] * 2048 / colsum[b][m])   (reuses zH region)
  u16* eT = zH;
  k_et<<<dim3(DD / 64, NE / 64, BB), 256, 0, stream>>>(eH, cs, eT);

  // out[b] = (S[b] @ eT[b]^T) / 2048 ; 1024 blocks
  k_gemm<2, 2048><<<dim3(DD / 128, NZ / 128, BB), 256, 49152, stream>>>(
      S, eT, out, DD,
      (long long)NZ * NE, (long long)DD * NE, (long long)NZ * DD, nullptr, 0);
}